// Round 4
// baseline (119.737 us; speedup 1.0000x reference)
//
#include <hip/hip_runtime.h>
#include <hip/hip_bf16.h>
#include <hip/hip_fp16.h>

// Problem constants
#define BB 16
#define TT 64
#define NN 2048
#define HH 32
#define DD 16
#define LAG 7
#define KTILE 128
#define NSPLIT 4
#define KSPLIT (NN / NSPLIT)   // 512 keys per block
#define PSTRIDE 36             // floats per (row,split) partial record (144B, 16B-aligned)

typedef _Float16 h16;
typedef __attribute__((ext_vector_type(8))) _Float16 hfrag;
typedef __attribute__((ext_vector_type(4))) float f32x4;

#define LOG2E 1.44269504088896f

// ---------------------------------------------------------------------------
// Kernel 1: projections -> fp16 Q,K (row-major [b][n][16]), V^T ([b][h][n]),
// plus temporal delay-weighted term (f32). One thread per (b,n).
// ---------------------------------------------------------------------------
__global__ __launch_bounds__(256) void proj_kernel(
    const float* __restrict__ x, const float* __restrict__ feat,
    const float* __restrict__ dlw,
    const float* __restrict__ Wk, const float* __restrict__ bk,
    const float* __restrict__ Wq, const float* __restrict__ bq,
    const float* __restrict__ Wv, const float* __restrict__ bv,
    h16* __restrict__ Qh, h16* __restrict__ Kh, h16* __restrict__ VTh,
    float* __restrict__ Wbuf)
{
    __shared__ float sWk[HH*DD], sWq[HH*DD], sWv[HH*HH];
    for (int i = threadIdx.x; i < HH*DD; i += 256) { sWk[i] = Wk[i]; sWq[i] = Wq[i]; }
    for (int i = threadIdx.x; i < HH*HH; i += 256) sWv[i] = Wv[i];
    __syncthreads();

    const int tid = blockIdx.x * 256 + threadIdx.x;   // 0 .. B*N-1
    const int b = tid >> 11;
    const int n = tid & (NN - 1);

    float f[HH];
    {
        const float4* fp = (const float4*)(feat + (size_t)tid * HH);
        #pragma unroll
        for (int i = 0; i < 8; ++i) {
            float4 v = fp[i];
            f[4*i+0] = v.x; f[4*i+1] = v.y; f[4*i+2] = v.z; f[4*i+3] = v.w;
        }
    }

    // q, k projections (H=32 -> D=16)
    float qa[DD], ka[DD];
    #pragma unroll
    for (int d = 0; d < DD; ++d) { qa[d] = bq[d]; ka[d] = bk[d]; }
    #pragma unroll
    for (int h = 0; h < HH; ++h) {
        const float fh = f[h];
        #pragma unroll
        for (int d = 0; d < DD; ++d) {
            qa[d] += fh * sWq[h*DD + d];
            ka[d] += fh * sWk[h*DD + d];
        }
    }
    {
        hfrag q0, q1, k0, k1;
        #pragma unroll
        for (int i = 0; i < 8; ++i) {
            q0[i] = (h16)qa[i];   q1[i] = (h16)qa[8+i];
            k0[i] = (h16)ka[i];   k1[i] = (h16)ka[8+i];
        }
        *(hfrag*)(Qh + (size_t)tid * DD)     = q0;
        *(hfrag*)(Qh + (size_t)tid * DD + 8) = q1;
        *(hfrag*)(Kh + (size_t)tid * DD)     = k0;
        *(hfrag*)(Kh + (size_t)tid * DD + 8) = k1;
    }

    // v projection (H=32 -> 32), stored transposed [b][h][n]
    float va[HH];
    #pragma unroll
    for (int j = 0; j < HH; ++j) va[j] = bv[j];
    #pragma unroll
    for (int h = 0; h < HH; ++h) {
        const float fh = f[h];
        #pragma unroll
        for (int j = 0; j < HH; ++j) va[j] += fh * sWv[h*HH + j];
    }
    {
        h16* vb = VTh + (size_t)b * HH * NN;
        #pragma unroll
        for (int j = 0; j < HH; ++j) vb[(size_t)j*NN + n] = (h16)va[j];
    }

    // temporal delay-weighted sum
    float w[LAG];
    float mx = dlw[0];
    #pragma unroll
    for (int t = 1; t < LAG; ++t) mx = fmaxf(mx, dlw[t]);
    float sum = 0.f;
    #pragma unroll
    for (int t = 0; t < LAG; ++t) { w[t] = __expf(dlw[t] - mx); sum += w[t]; }
    const float inv = 1.f / sum;
    float acc = 0.f;
    #pragma unroll
    for (int t = 0; t < LAG; ++t)
        acc += w[t] * inv * x[(size_t)b * TT * NN + (size_t)(TT - 1 - t) * NN + n];
    Wbuf[tid] = acc;
}

// ---------------------------------------------------------------------------
// Kernel 2: split-K attention partial, NO-MAX softmax (scores provably
// bounded: |0.106*qk + 0.574*adj| < ~4, exp safe in f32; algebraically
// identical to max-subtracted softmax).
// Grid: 128 qt x 4 bg x 4 split = 2048 blocks; 4 waves/block; VGPR<=64 via
// launch_bounds -> 8 blocks/CU -> entire grid co-resident.
// Single pass per 16-col tile: S -> blend+exp2 -> LDS -> PV.
// MFMA 16x16x32 fp16; C-layout: col=lane&15, row=(lane>>4)*4+reg.
// ---------------------------------------------------------------------------
__global__ __launch_bounds__(256, 8) void attn_kernel(
    const h16* __restrict__ Qh, const h16* __restrict__ Kh,
    const h16* __restrict__ VTh, const float* __restrict__ adj,
    const float* __restrict__ awp, float* __restrict__ part)
{
    const int id    = blockIdx.x;
    const int qt    = id >> 4;           // 0..127
    const int bg    = (id >> 2) & 3;     // 0..3
    const int split = id & 3;            // 0..3
    const int wave  = threadIdx.x >> 6;
    const int lane  = threadIdx.x & 63;
    const int b     = bg * 4 + wave;
    const int q0r   = qt * 16;
    const int l = lane & 15, g = lane >> 4;

    __shared__ __attribute__((aligned(16))) h16 Pl_all[4][16][136];
    h16 (* __restrict__ Pl)[136] = Pl_all[wave];

    const float blendv = 1.f / (1.f + __expf(-awp[0]));
    const float c1 = (1.f - blendv) * 0.25f * LOG2E;   // folds 1/sqrt(D) and log2(e)
    const float c2 = blendv * LOG2E;

    const h16* Qb = Qh + (size_t)b * NN * DD;
    const h16* Kb = Kh + (size_t)b * NN * DD;
    const h16* Vb = VTh + (size_t)b * HH * NN;
    const float* arow = adj + (size_t)q0r * NN + g * 4 * NN + l;  // row q0r+g*4, col l

    const hfrag hz = {(h16)0,(h16)0,(h16)0,(h16)0,(h16)0,(h16)0,(h16)0,(h16)0};
    const f32x4 zero4 = {0.f, 0.f, 0.f, 0.f};

    // Q A-fragment: row = l, k(d) = g*8+j ; d>=16 zero padding
    hfrag qf = hz;
    if (g < 2) qf = *(const hfrag*)(Qb + (size_t)(q0r + l) * DD + g * 8);

    f32x4 o0 = zero4, o1 = zero4;
    float l_run[4] = {0.f, 0.f, 0.f, 0.f};

    const int k0 = split * KSPLIT;
    #pragma unroll 1
    for (int kt = k0; kt < k0 + KSPLIT; kt += KTILE) {
        // ---- per 16-col tile: S = QK^T, blend adj, exp2, stash P ----
        #pragma unroll
        for (int c = 0; c < 8; ++c) {
            hfrag kf = hz;
            if (g < 2) kf = *(const hfrag*)(Kb + (size_t)(kt + c*16 + l) * DD + g * 8);
            const f32x4 s = __builtin_amdgcn_mfma_f32_16x16x32_f16(qf, kf, zero4, 0, 0, 0);
            #pragma unroll
            for (int r = 0; r < 4; ++r) {
                const float a = arow[(size_t)r * NN + kt + c*16];
                const float p = __builtin_amdgcn_exp2f(fmaf(c2, a, c1 * s[r]));
                l_run[r] += p;   // per-lane partial; reduced at the end
                Pl[g*4 + r][c*16 + l] = (h16)p;
            }
        }

        // ---- O += P @ V ----
        #pragma unroll
        for (int ch = 0; ch < 4; ++ch) {
            const hfrag pa = *(const hfrag*)(&Pl[l][ch*32 + g*8]);
            const hfrag v0 = *(const hfrag*)(Vb + (size_t)l        * NN + kt + ch*32 + g*8);
            const hfrag v1 = *(const hfrag*)(Vb + (size_t)(16 + l) * NN + kt + ch*32 + g*8);
            o0 = __builtin_amdgcn_mfma_f32_16x16x32_f16(pa, v0, o0, 0, 0, 0);
            o1 = __builtin_amdgcn_mfma_f32_16x16x32_f16(pa, v1, o1, 0, 0, 0);
        }
    }

    // ---- reduce l partials across the 16 lanes of each group ----
    #pragma unroll
    for (int r = 0; r < 4; ++r) {
        #pragma unroll
        for (int off = 1; off < 16; off <<= 1)
            l_run[r] += __shfl_xor(l_run[r], off, 64);
    }

    // ---- write partial records: [row][split] -> {o[32], l} ----
    #pragma unroll
    for (int r = 0; r < 4; ++r) {
        float* rp = part + ((size_t)(b * NN + q0r + g*4 + r) * NSPLIT + split) * PSTRIDE;
        rp[l]      = o0[r];
        rp[16 + l] = o1[r];
        if (l == 0) rp[32] = l_run[r];
    }
}

// ---------------------------------------------------------------------------
// Kernel 3: combine 4 split partials (plain sums — no max needed) +
// temporal add + out_proj + LayerNorm. 4 lanes per row.
// ---------------------------------------------------------------------------
__global__ __launch_bounds__(256) void combine_kernel(
    const float* __restrict__ part, const float* __restrict__ Wbuf,
    const float* __restrict__ Wo, const float* __restrict__ bo,
    const float* __restrict__ lng, const float* __restrict__ lnb,
    float* __restrict__ out)
{
    __shared__ float sWo[HH*HH];
    __shared__ float sbo[HH], sg[HH], sb[HH];
    for (int i = threadIdx.x; i < HH*HH; i += 256) sWo[i] = Wo[i];
    if (threadIdx.x < HH) {
        sbo[threadIdx.x] = bo[threadIdx.x];
        sg[threadIdx.x]  = lng[threadIdx.x];
        sb[threadIdx.x]  = lnb[threadIdx.x];
    }
    __syncthreads();

    const int rid = blockIdx.x * 64 + (threadIdx.x >> 2);  // 0..B*N-1
    const int jg  = threadIdx.x & 3;

    const float* rp = part + ((size_t)rid * NSPLIT + jg) * PSTRIDE;
    float o[HH];
    #pragma unroll
    for (int i = 0; i < 8; ++i) {
        float4 v = *(const float4*)(rp + i*4);
        o[4*i+0] = v.x; o[4*i+1] = v.y; o[4*i+2] = v.z; o[4*i+3] = v.w;
    }
    float lsum = rp[32];
    lsum += __shfl_xor(lsum, 1, 64);
    lsum += __shfl_xor(lsum, 2, 64);

    #pragma unroll
    for (int c = 0; c < HH; ++c) {
        o[c] += __shfl_xor(o[c], 1, 64);
        o[c] += __shfl_xor(o[c], 2, 64);
    }

    const float wgt = Wbuf[rid] * 0.1f;
    const float inv = 1.f / lsum;
    float pr[HH];
    #pragma unroll
    for (int c = 0; c < HH; ++c) pr[c] = fmaf(o[c], inv, wgt);

    // Wo GEMM: 8 output columns per lane
    float acc[8];
    #pragma unroll
    for (int j = 0; j < 8; ++j) acc[j] = sbo[jg*8 + j];
    #pragma unroll
    for (int h = 0; h < HH; ++h) {
        #pragma unroll
        for (int j = 0; j < 8; ++j)
            acc[j] = fmaf(pr[h], sWo[h*HH + jg*8 + j], acc[j]);
    }

    // LayerNorm across the 4 lanes (32 values)
    float ss = 0.f, sq = 0.f;
    #pragma unroll
    for (int j = 0; j < 8; ++j) { ss += acc[j]; sq += acc[j]*acc[j]; }
    ss += __shfl_xor(ss, 1, 64); ss += __shfl_xor(ss, 2, 64);
    sq += __shfl_xor(sq, 1, 64); sq += __shfl_xor(sq, 2, 64);
    const float mean = ss * (1.f / HH);
    const float var  = sq * (1.f / HH) - mean * mean;
    const float rstd = rsqrtf(var + 1e-5f);

    float res[8];
    #pragma unroll
    for (int j = 0; j < 8; ++j)
        res[j] = (acc[j] - mean) * rstd * sg[jg*8 + j] + sb[jg*8 + j];

    float* op = out + (size_t)rid * HH + jg * 8;
    *(float4*)(op)     = make_float4(res[0], res[1], res[2], res[3]);
    *(float4*)(op + 4) = make_float4(res[4], res[5], res[6], res[7]);
}

// ---------------------------------------------------------------------------
extern "C" void kernel_launch(void* const* d_in, const int* in_sizes, int n_in,
                              void* d_out, int out_size, void* d_ws, size_t ws_size,
                              hipStream_t stream)
{
    const float* x    = (const float*)d_in[0];
    const float* feat = (const float*)d_in[1];
    const float* adj  = (const float*)d_in[2];
    const float* dlw  = (const float*)d_in[3];
    const float* aw   = (const float*)d_in[4];
    const float* Wk   = (const float*)d_in[5];
    const float* bk   = (const float*)d_in[6];
    const float* Wq   = (const float*)d_in[7];
    const float* bq   = (const float*)d_in[8];
    const float* Wv   = (const float*)d_in[9];
    const float* bv   = (const float*)d_in[10];
    const float* Wo   = (const float*)d_in[11];
    const float* bo   = (const float*)d_in[12];
    const float* lng  = (const float*)d_in[13];
    const float* lnb  = (const float*)d_in[14];

    h16* Qh  = (h16*)d_ws;                   // B*N*16 h16   = 1 MB
    h16* Kh  = Qh + 524288;                  // 1 MB
    h16* VTh = Kh + 524288;                  // B*32*N h16   = 2 MB
    float* Wb = (float*)(VTh + 1048576);     // B*N f32      = 128 KB
    float* part = Wb + 32768;                // B*N*4*36 f32 = 18.9 MB
    float* out = (float*)d_out;

    proj_kernel<<<(BB*NN)/256, 256, 0, stream>>>(x, feat, dlw, Wk, bk, Wq, bq,
                                                 Wv, bv, Qh, Kh, VTh, Wb);
    attn_kernel<<<128*4*NSPLIT, 256, 0, stream>>>(Qh, Kh, VTh, adj, aw, part);
    combine_kernel<<<(BB*NN)/64, 256, 0, stream>>>(part, Wb, Wo, bo, lng, lnb, out);
}

// Round 6
// 62.200 us; speedup vs baseline: 1.9250x; 1.9250x over previous
//
#include <hip/hip_runtime.h>
#include <hip/hip_bf16.h>
#include <hip/hip_fp16.h>

// Problem constants
#define BB 16
#define TT 64
#define NN 2048
#define HH 32
#define DD 16
#define LAG 7
#define NSPLIT 4
#define KSPLIT (NN / NSPLIT)   // 512 keys per wave
#define LOG2E 1.44269504088896f

typedef _Float16 h16;
typedef __attribute__((ext_vector_type(8))) _Float16 hfrag;
typedef __attribute__((ext_vector_type(2))) __fp16 fp16x2;
typedef __attribute__((ext_vector_type(16))) float f32x16;

static __device__ __forceinline__ unsigned pkh(float a, float b) {
    union { fp16x2 h; unsigned u; } x;
    x.h = __builtin_amdgcn_cvt_pkrtz(a, b);
    return x.u;
}
static __device__ __forceinline__ hfrag frag4(unsigned w0, unsigned w1,
                                              unsigned w2, unsigned w3) {
    union { unsigned u[4]; hfrag h; } x;
    x.u[0] = w0; x.u[1] = w1; x.u[2] = w2; x.u[3] = w3;
    return x.h;
}

// ---------------------------------------------------------------------------
// Kernel 1: projections. Q is PRESCALED by (1-blend)*0.25*log2e (folds the
// softmax blend + 1/sqrt(D) + exp2 conversion into the QK MFMA).
// Q,K row-major fp16 [b][n][16]; V^T fp16 [b][h][n]; temporal term f32.
// ---------------------------------------------------------------------------
__global__ __launch_bounds__(256) void proj_kernel(
    const float* __restrict__ x, const float* __restrict__ feat,
    const float* __restrict__ dlw, const float* __restrict__ awp,
    const float* __restrict__ Wk, const float* __restrict__ bk,
    const float* __restrict__ Wq, const float* __restrict__ bq,
    const float* __restrict__ Wv, const float* __restrict__ bv,
    h16* __restrict__ Qh, h16* __restrict__ Kh, h16* __restrict__ VTh,
    float* __restrict__ Wbuf)
{
    __shared__ float sWk[HH*DD], sWq[HH*DD], sWv[HH*HH];
    for (int i = threadIdx.x; i < HH*DD; i += 256) { sWk[i] = Wk[i]; sWq[i] = Wq[i]; }
    for (int i = threadIdx.x; i < HH*HH; i += 256) sWv[i] = Wv[i];
    __syncthreads();

    const float blend = 1.f / (1.f + __expf(-awp[0]));
    const float qscale = (1.f - blend) * 0.25f * LOG2E;

    const int tid = blockIdx.x * 256 + threadIdx.x;   // 0 .. B*N-1
    const int b = tid >> 11;
    const int n = tid & (NN - 1);

    float f[HH];
    {
        const float4* fp = (const float4*)(feat + (size_t)tid * HH);
        #pragma unroll
        for (int i = 0; i < 8; ++i) {
            float4 v = fp[i];
            f[4*i+0] = v.x; f[4*i+1] = v.y; f[4*i+2] = v.z; f[4*i+3] = v.w;
        }
    }

    float qa[DD], ka[DD];
    #pragma unroll
    for (int d = 0; d < DD; ++d) { qa[d] = bq[d]; ka[d] = bk[d]; }
    #pragma unroll
    for (int h = 0; h < HH; ++h) {
        const float fh = f[h];
        #pragma unroll
        for (int d = 0; d < DD; ++d) {
            qa[d] += fh * sWq[h*DD + d];
            ka[d] += fh * sWk[h*DD + d];
        }
    }
    {
        hfrag q0, q1, k0, k1;
        #pragma unroll
        for (int i = 0; i < 8; ++i) {
            q0[i] = (h16)(qa[i] * qscale);   q1[i] = (h16)(qa[8+i] * qscale);
            k0[i] = (h16)ka[i];              k1[i] = (h16)ka[8+i];
        }
        *(hfrag*)(Qh + (size_t)tid * DD)     = q0;
        *(hfrag*)(Qh + (size_t)tid * DD + 8) = q1;
        *(hfrag*)(Kh + (size_t)tid * DD)     = k0;
        *(hfrag*)(Kh + (size_t)tid * DD + 8) = k1;
    }

    float va[HH];
    #pragma unroll
    for (int j = 0; j < HH; ++j) va[j] = bv[j];
    #pragma unroll
    for (int h = 0; h < HH; ++h) {
        const float fh = f[h];
        #pragma unroll
        for (int j = 0; j < HH; ++j) va[j] += fh * sWv[h*HH + j];
    }
    {
        h16* vb = VTh + (size_t)b * HH * NN;
        #pragma unroll
        for (int j = 0; j < HH; ++j) vb[(size_t)j*NN + n] = (h16)va[j];
    }

    // temporal delay-weighted sum
    float w[LAG];
    float mx = dlw[0];
    #pragma unroll
    for (int t = 1; t < LAG; ++t) mx = fmaxf(mx, dlw[t]);
    float sum = 0.f;
    #pragma unroll
    for (int t = 0; t < LAG; ++t) { w[t] = __expf(dlw[t] - mx); sum += w[t]; }
    const float inv = 1.f / sum;
    float acc = 0.f;
    #pragma unroll
    for (int t = 0; t < LAG; ++t)
        acc += w[t] * inv * x[(size_t)b * TT * NN + (size_t)(TT - 1 - t) * NN + n];
    Wbuf[tid] = acc;
}

// ---------------------------------------------------------------------------
// Kernel 1b: adjT[m][n] = blend*log2e * adj[n][m], stored fp16 (values are
// ~1e-3: fp16 rel error contributes <1e-6 to the exp2 argument).
// Standard 32x32 LDS-tiled transpose; 64x64 blocks of 256 threads.
// ---------------------------------------------------------------------------
__global__ __launch_bounds__(256) void adjt_kernel(
    const float* __restrict__ adj, const float* __restrict__ awp,
    h16* __restrict__ adjT)
{
    __shared__ float t[32][33];
    const float blend = 1.f / (1.f + __expf(-awp[0]));
    const float scale = blend * LOG2E;
    const int bx = blockIdx.x, by = blockIdx.y;
    const int tx = threadIdx.x & 31, ty = threadIdx.x >> 5;   // 32 x 8
    #pragma unroll
    for (int i = 0; i < 4; ++i)
        t[ty + i*8][tx] = adj[(size_t)(by*32 + ty + i*8) * NN + bx*32 + tx];
    __syncthreads();
    #pragma unroll
    for (int i = 0; i < 4; ++i)
        adjT[(size_t)(bx*32 + ty + i*8) * NN + by*32 + tx] =
            (h16)(scale * t[tx][ty + i*8]);
}

// ---------------------------------------------------------------------------
// Kernel 2: split-K attention, 32x32x16 MFMA, swapped operands, zero LDS.
//   S = mfma(A=K_tile, B=Q_scaled, C=adjT_scaled)   [no-max softmax: |S|<~4]
//   P = exp2(S) held per-lane (lane l owns q-row l); C->A layout fix-up via
//   cvt_pkrtz pairs + shfl_xor(32) exchange; O += mfma(P_chunk, V_chunk, O).
// Grid: 64 qt x 4 bg x 4 split = 1024 blocks x 4 waves (wave = batch).
// C-layout (m74/m101): col=lane&31, row=(reg&3)+8*(reg>>2)+4*(lane>>5).
// A/B-layout: row/col=lane&31, k=(lane>>5)*8+j.
// ---------------------------------------------------------------------------
__global__ __launch_bounds__(256, 4) void attn_kernel(
    const h16* __restrict__ Qh, const h16* __restrict__ Kh,
    const h16* __restrict__ VTh, const h16* __restrict__ adjT,
    float* __restrict__ part, float* __restrict__ lpart)
{
    const int id    = blockIdx.x;         // qt(64) x bg(4) x split(4)
    const int qt    = id >> 4;
    const int bg    = (id >> 2) & 3;
    const int split = id & 3;
    const int wave  = threadIdx.x >> 6;
    const int lane  = threadIdx.x & 63;
    const int b     = bg * 4 + wave;
    const int q0    = qt * 32;
    const int l = lane & 31, g = lane >> 5;
    const bool g1 = (g != 0);

    const h16* Qb = Qh + (size_t)b * NN * DD;
    const h16* Kb = Kh + (size_t)b * NN * DD;
    const h16* Vb = VTh + (size_t)b * HH * NN + (size_t)l * NN;  // row h = l
    const h16* aT = adjT + q0 + l;                               // + key*NN

    // Q B-fragment: col(q)=l, k(d)=g*8+j — 16B contiguous
    const hfrag qf = *(const hfrag*)(Qb + (size_t)(q0 + l) * DD + g * 8);

    f32x16 O;
    #pragma unroll
    for (int r = 0; r < 16; ++r) O[r] = 0.f;
    float lsum = 0.f;   // softmax denom partial for q-row l (this half's keys)

    const int k0 = split * KSPLIT;
    #pragma unroll 1
    for (int kt = k0; kt < k0 + KSPLIT; kt += 32) {
        // ---- C preload: S[r] = adjT[kt+key][q0+l], key=(r&3)+8*(r>>2)+4g ----
        f32x16 S;
        #pragma unroll
        for (int r = 0; r < 16; ++r) {
            const int key = (r & 3) + 8 * (r >> 2) + 4 * g;
            S[r] = (float)aT[(size_t)(kt + key) * NN];
        }
        // K A-fragment: row(key)=l, k(d)=g*8+j
        const hfrag kf = *(const hfrag*)(Kb + (size_t)(kt + l) * DD + g * 8);
        S = __builtin_amdgcn_mfma_f32_32x32x16_f16(kf, qf, S, 0, 0, 0);

        // ---- P = exp2(S); lane l holds P[key set][q=l] ----
        float e[16];
        #pragma unroll
        for (int r = 0; r < 16; ++r) e[r] = __builtin_amdgcn_exp2f(S[r]);
        #pragma unroll
        for (int r = 0; r < 16; ++r) lsum += e[r];

        // pack pairs: W(t,w) covers keys 8t+4g+2w+{0,1}, t=r>>2
        const unsigned W0 = pkh(e[0],  e[1]),  W1 = pkh(e[2],  e[3]);
        const unsigned W2 = pkh(e[4],  e[5]),  W3 = pkh(e[6],  e[7]);
        const unsigned W4 = pkh(e[8],  e[9]),  W5 = pkh(e[10], e[11]);
        const unsigned W6 = pkh(e[12], e[13]), W7 = pkh(e[14], e[15]);

        // exchange complementary key-halves with lane^32
        const unsigned s0 = g1 ? W0 : W2;
        const unsigned s1 = g1 ? W1 : W3;
        const unsigned s2 = g1 ? W4 : W6;
        const unsigned s3 = g1 ? W5 : W7;
        const unsigned r0 = (unsigned)__shfl_xor((int)s0, 32, 64);
        const unsigned r1 = (unsigned)__shfl_xor((int)s1, 32, 64);
        const unsigned r2 = (unsigned)__shfl_xor((int)s2, 32, 64);
        const unsigned r3 = (unsigned)__shfl_xor((int)s3, 32, 64);

        // A-fragments for PV: row(q)=l, k(key)=g*8+j
        const hfrag pa0 = g1 ? frag4(r0, r1, W2, W3) : frag4(W0, W1, r0, r1);
        const hfrag pa1 = g1 ? frag4(r2, r3, W6, W7) : frag4(W4, W5, r2, r3);

        // V B-fragments: col(h)=l, k(key)=g*8+j — 16B contiguous from VT
        const hfrag v0 = *(const hfrag*)(Vb + kt + g * 8);
        const hfrag v1 = *(const hfrag*)(Vb + kt + 16 + g * 8);
        O = __builtin_amdgcn_mfma_f32_32x32x16_f16(pa0, v0, O, 0, 0, 0);
        O = __builtin_amdgcn_mfma_f32_32x32x16_f16(pa1, v1, O, 0, 0, 0);
    }

    // combine the two key-half partials of each q-row
    lsum += __shfl_xor(lsum, 32, 64);

    // ---- write partials: O rows are q=(r&3)+8*(r>>2)+4g, col h=l ----
    const size_t rec = (size_t)((b * 64 + qt) * NSPLIT + split);
    if (lane < 32) lpart[rec * 32 + lane] = lsum;
    float* pb = part + rec * 1024;
    #pragma unroll
    for (int r = 0; r < 16; ++r) {
        const int q = (r & 3) + 8 * (r >> 2) + 4 * g;
        pb[q * 32 + l] = O[r];
    }
}

// ---------------------------------------------------------------------------
// Kernel 3: combine 4 split partials + temporal add + out_proj + LayerNorm.
// 4 lanes per q-row; lane jg loads split jg, computes out cols jg*8..+7.
// ---------------------------------------------------------------------------
__global__ __launch_bounds__(256) void combine_kernel(
    const float* __restrict__ part, const float* __restrict__ lpart,
    const float* __restrict__ Wbuf,
    const float* __restrict__ Wo, const float* __restrict__ bo,
    const float* __restrict__ lng, const float* __restrict__ lnb,
    float* __restrict__ out)
{
    __shared__ float sWo[HH*HH];
    __shared__ float sbo[HH], sg[HH], sb[HH];
    for (int i = threadIdx.x; i < HH*HH; i += 256) sWo[i] = Wo[i];
    if (threadIdx.x < HH) {
        sbo[threadIdx.x] = bo[threadIdx.x];
        sg[threadIdx.x]  = lng[threadIdx.x];
        sb[threadIdx.x]  = lnb[threadIdx.x];
    }
    __syncthreads();

    const int rid = blockIdx.x * 64 + (threadIdx.x >> 2);  // 0..B*N-1
    const int jg  = threadIdx.x & 3;
    const int b   = rid >> 11;
    const int qt  = (rid >> 5) & 63;
    const int qr  = rid & 31;

    const size_t rec = (size_t)((b * 64 + qt) * NSPLIT + jg);
    const float* rp = part + rec * 1024 + qr * 32;
    float o[HH];
    #pragma unroll
    for (int i = 0; i < 8; ++i) {
        float4 v = *(const float4*)(rp + i*4);
        o[4*i+0] = v.x; o[4*i+1] = v.y; o[4*i+2] = v.z; o[4*i+3] = v.w;
    }
    float lsum = lpart[rec * 32 + qr];
    lsum += __shfl_xor(lsum, 1, 64);
    lsum += __shfl_xor(lsum, 2, 64);
    #pragma unroll
    for (int c = 0; c < HH; ++c) {
        o[c] += __shfl_xor(o[c], 1, 64);
        o[c] += __shfl_xor(o[c], 2, 64);
    }

    const float wgt = Wbuf[rid] * 0.1f;
    const float inv = 1.f / lsum;
    float pr[HH];
    #pragma unroll
    for (int c = 0; c < HH; ++c) pr[c] = fmaf(o[c], inv, wgt);

    float acc[8];
    #pragma unroll
    for (int j = 0; j < 8; ++j) acc[j] = sbo[jg*8 + j];
    #pragma unroll
    for (int h = 0; h < HH; ++h) {
        #pragma unroll
        for (int j = 0; j < 8; ++j)
            acc[j] = fmaf(pr[h], sWo[h*HH + jg*8 + j], acc[j]);
    }

    float ss = 0.f, sq = 0.f;
    #pragma unroll
    for (int j = 0; j < 8; ++j) { ss += acc[j]; sq += acc[j]*acc[j]; }
    ss += __shfl_xor(ss, 1, 64); ss += __shfl_xor(ss, 2, 64);
    sq += __shfl_xor(sq, 1, 64); sq += __shfl_xor(sq, 2, 64);
    const float mean = ss * (1.f / HH);
    const float var  = sq * (1.f / HH) - mean * mean;
    const float rstd = rsqrtf(var + 1e-5f);

    float res[8];
    #pragma unroll
    for (int j = 0; j < 8; ++j)
        res[j] = (acc[j] - mean) * rstd * sg[jg*8 + j] + sb[jg*8 + j];

    float* op = out + (size_t)rid * HH + jg * 8;
    *(float4*)(op)     = make_float4(res[0], res[1], res[2], res[3]);
    *(float4*)(op + 4) = make_float4(res[4], res[5], res[6], res[7]);
}

// ---------------------------------------------------------------------------
extern "C" void kernel_launch(void* const* d_in, const int* in_sizes, int n_in,
                              void* d_out, int out_size, void* d_ws, size_t ws_size,
                              hipStream_t stream)
{
    const float* x    = (const float*)d_in[0];
    const float* feat = (const float*)d_in[1];
    const float* adj  = (const float*)d_in[2];
    const float* dlw  = (const float*)d_in[3];
    const float* aw   = (const float*)d_in[4];
    const float* Wk   = (const float*)d_in[5];
    const float* bk   = (const float*)d_in[6];
    const float* Wq   = (const float*)d_in[7];
    const float* bq   = (const float*)d_in[8];
    const float* Wv   = (const float*)d_in[9];
    const float* bv   = (const float*)d_in[10];
    const float* Wo   = (const float*)d_in[11];
    const float* bo   = (const float*)d_in[12];
    const float* lng  = (const float*)d_in[13];
    const float* lnb  = (const float*)d_in[14];

    h16* Qh   = (h16*)d_ws;                     // 524288 h16 (1 MB)
    h16* Kh   = Qh + 524288;                    // 1 MB
    h16* VTh  = Kh + 524288;                    // 1048576 h16 (2 MB)
    float* Wb = (float*)(VTh + 1048576);        // 32768 f32 (128 KB)
    h16* adjT = (h16*)(Wb + 32768);             // NN*NN h16 (8 MB)
    float* part  = (float*)(adjT + (size_t)NN*NN);  // 16*64*4*1024 f32 (16 MB)
    float* lpart = part + 4194304;              // 131072 f32 (512 KB)
    float* out = (float*)d_out;

    proj_kernel<<<(BB*NN)/256, 256, 0, stream>>>(x, feat, dlw, aw, Wk, bk, Wq, bq,
                                                 Wv, bv, Qh, Kh, VTh, Wb);
    adjt_kernel<<<dim3(64, 64), 256, 0, stream>>>(adj, aw, adjT);
    attn_kernel<<<64*4*NSPLIT, 256, 0, stream>>>(Qh, Kh, VTh, adjT, part, lpart);
    combine_kernel<<<(BB*NN)/64, 256, 0, stream>>>(part, lpart, Wb, Wo, bo,
                                                   lng, lnb, out);
}

// Round 7
// 58.427 us; speedup vs baseline: 2.0494x; 1.0646x over previous
//
#include <hip/hip_runtime.h>
#include <hip/hip_bf16.h>
#include <hip/hip_fp16.h>

// Problem constants
#define BB 16
#define TT 64
#define NN 2048
#define HH 32
#define DD 16
#define LAG 7
#define NSPLIT 4
#define KSPLIT (NN / NSPLIT)   // 512 keys per wave
#define LOG2E 1.44269504088896f

typedef _Float16 h16;
typedef __attribute__((ext_vector_type(8))) _Float16 hfrag;
typedef __attribute__((ext_vector_type(2))) __fp16 fp16x2;
typedef __attribute__((ext_vector_type(16))) float f32x16;

static __device__ __forceinline__ unsigned pkh(float a, float b) {
    union { fp16x2 h; unsigned u; } x;
    x.h = __builtin_amdgcn_cvt_pkrtz(a, b);
    return x.u;
}
static __device__ __forceinline__ hfrag frag4(unsigned w0, unsigned w1,
                                              unsigned w2, unsigned w3) {
    union { unsigned u[4]; hfrag h; } x;
    x.u[0] = w0; x.u[1] = w1; x.u[2] = w2; x.u[3] = w3;
    return x.h;
}

// ---------------------------------------------------------------------------
// Kernel 1: projections. Q is PRESCALED by (1-blend)*0.25*log2e (folds the
// softmax blend + 1/sqrt(D) + exp2 conversion into the QK MFMA).
// Q,K row-major fp16 [b][n][16]; V^T fp16 [b][h][n]; temporal term f32.
// ---------------------------------------------------------------------------
__global__ __launch_bounds__(256) void proj_kernel(
    const float* __restrict__ x, const float* __restrict__ feat,
    const float* __restrict__ dlw, const float* __restrict__ awp,
    const float* __restrict__ Wk, const float* __restrict__ bk,
    const float* __restrict__ Wq, const float* __restrict__ bq,
    const float* __restrict__ Wv, const float* __restrict__ bv,
    h16* __restrict__ Qh, h16* __restrict__ Kh, h16* __restrict__ VTh,
    float* __restrict__ Wbuf)
{
    __shared__ float sWk[HH*DD], sWq[HH*DD], sWv[HH*HH];
    for (int i = threadIdx.x; i < HH*DD; i += 256) { sWk[i] = Wk[i]; sWq[i] = Wq[i]; }
    for (int i = threadIdx.x; i < HH*HH; i += 256) sWv[i] = Wv[i];
    __syncthreads();

    const float blend = 1.f / (1.f + __expf(-awp[0]));
    const float qscale = (1.f - blend) * 0.25f * LOG2E;

    const int tid = blockIdx.x * 256 + threadIdx.x;   // 0 .. B*N-1
    const int b = tid >> 11;
    const int n = tid & (NN - 1);

    float f[HH];
    {
        const float4* fp = (const float4*)(feat + (size_t)tid * HH);
        #pragma unroll
        for (int i = 0; i < 8; ++i) {
            float4 v = fp[i];
            f[4*i+0] = v.x; f[4*i+1] = v.y; f[4*i+2] = v.z; f[4*i+3] = v.w;
        }
    }

    float qa[DD], ka[DD];
    #pragma unroll
    for (int d = 0; d < DD; ++d) { qa[d] = bq[d]; ka[d] = bk[d]; }
    #pragma unroll
    for (int h = 0; h < HH; ++h) {
        const float fh = f[h];
        #pragma unroll
        for (int d = 0; d < DD; ++d) {
            qa[d] += fh * sWq[h*DD + d];
            ka[d] += fh * sWk[h*DD + d];
        }
    }
    {
        hfrag q0, q1, k0, k1;
        #pragma unroll
        for (int i = 0; i < 8; ++i) {
            q0[i] = (h16)(qa[i] * qscale);   q1[i] = (h16)(qa[8+i] * qscale);
            k0[i] = (h16)ka[i];              k1[i] = (h16)ka[8+i];
        }
        *(hfrag*)(Qh + (size_t)tid * DD)     = q0;
        *(hfrag*)(Qh + (size_t)tid * DD + 8) = q1;
        *(hfrag*)(Kh + (size_t)tid * DD)     = k0;
        *(hfrag*)(Kh + (size_t)tid * DD + 8) = k1;
    }

    float va[HH];
    #pragma unroll
    for (int j = 0; j < HH; ++j) va[j] = bv[j];
    #pragma unroll
    for (int h = 0; h < HH; ++h) {
        const float fh = f[h];
        #pragma unroll
        for (int j = 0; j < HH; ++j) va[j] += fh * sWv[h*HH + j];
    }
    {
        h16* vb = VTh + (size_t)b * HH * NN;
        #pragma unroll
        for (int j = 0; j < HH; ++j) vb[(size_t)j*NN + n] = (h16)va[j];
    }

    // temporal delay-weighted sum
    float w[LAG];
    float mx = dlw[0];
    #pragma unroll
    for (int t = 1; t < LAG; ++t) mx = fmaxf(mx, dlw[t]);
    float sum = 0.f;
    #pragma unroll
    for (int t = 0; t < LAG; ++t) { w[t] = __expf(dlw[t] - mx); sum += w[t]; }
    const float inv = 1.f / sum;
    float acc = 0.f;
    #pragma unroll
    for (int t = 0; t < LAG; ++t)
        acc += w[t] * inv * x[(size_t)b * TT * NN + (size_t)(TT - 1 - t) * NN + n];
    Wbuf[tid] = acc;
}

// ---------------------------------------------------------------------------
// Kernel 1b: pack adj into MFMA C-fragment order, scaled by blend*log2e:
//   adjP[((qt*64 + kti)*64 + lane)*16 + r] = sc * adj[qt*32 + (lane&31)]
//                                               [kti*32 + key(r, lane>>5)]
// where key(r,g) = (r&3) + 8*(r>>2) + 4*g  (32x32x16 C-layout, m74/m101).
// Per-lane 32B contiguous -> attn reads 2 coalesced b128 per 32-key tile.
// Block: one qt x 128 keys, staged via LDS [32][129] (padded, conflict-free).
// ---------------------------------------------------------------------------
__global__ __launch_bounds__(256) void adjp_kernel(
    const float* __restrict__ adj, const float* __restrict__ awp,
    h16* __restrict__ adjP)
{
    __shared__ float s[32][129];
    const float blend = 1.f / (1.f + __expf(-awp[0]));
    const float sc = blend * LOG2E;
    const int qt = blockIdx.x;        // 0..63
    const int kg = blockIdx.y;        // 0..15 (128-key group)
    const int t  = threadIdx.x;

    const int row = t >> 3;           // 0..31
    const int qd  = t & 7;            // 0..7
    const float* ap = adj + (size_t)(qt*32 + row)*NN + kg*128 + qd*16;
    #pragma unroll
    for (int i = 0; i < 4; ++i) {
        const float4 v = *(const float4*)(ap + i*4);
        s[row][qd*16 + i*4 + 0] = v.x;
        s[row][qd*16 + i*4 + 1] = v.y;
        s[row][qd*16 + i*4 + 2] = v.z;
        s[row][qd*16 + i*4 + 3] = v.w;
    }
    __syncthreads();

    const int kl   = t >> 6;          // 0..3 local ktile
    const int lane = t & 63;
    const int l = lane & 31, g = lane >> 5;
    hfrag o0, o1;
    #pragma unroll
    for (int r = 0; r < 8; ++r) {
        const int k0 = (r & 3) + 8 * (r >> 2) + 4 * g;
        const int k1 = ((r+8) & 3) + 8 * ((r+8) >> 2) + 4 * g;
        o0[r] = (h16)(sc * s[l][kl*32 + k0]);
        o1[r] = (h16)(sc * s[l][kl*32 + k1]);
    }
    h16* op = adjP + ((size_t)((qt*64 + kg*4 + kl)*64) + lane) * 16;
    *(hfrag*)(op)     = o0;
    *(hfrag*)(op + 8) = o1;
}

// ---------------------------------------------------------------------------
// Kernel 2: split-K attention, 32x32x16 MFMA, swapped operands, zero LDS,
// 1-deep register prefetch of K/adjP/V fragments (hides L2/L3 latency).
//   S = mfma(A=K_tile, B=Q_scaled, C=cvt(adjP))   [no-max softmax: |S|<~4]
//   P = exp2(S); C->A fix-up via cvt_pkrtz + shfl_xor(32); O += mfma(P,V,O).
// Grid: 64 qt x 4 bg x 4 split = 1024 blocks x 4 waves (wave = batch).
// ---------------------------------------------------------------------------
__global__ __launch_bounds__(256, 4) void attn_kernel(
    const h16* __restrict__ Qh, const h16* __restrict__ Kh,
    const h16* __restrict__ VTh, const h16* __restrict__ adjP,
    float* __restrict__ part, float* __restrict__ lpart)
{
    const int id    = blockIdx.x;         // qt(64) x bg(4) x split(4)
    const int qt    = id >> 4;
    const int bg    = (id >> 2) & 3;
    const int split = id & 3;
    const int wave  = threadIdx.x >> 6;
    const int lane  = threadIdx.x & 63;
    const int b     = bg * 4 + wave;
    const int q0    = qt * 32;
    const int l = lane & 31, g = lane >> 5;
    const bool g1 = (g != 0);

    const h16* Qb = Qh + (size_t)b * NN * DD;
    const h16* Kb = Kh + (size_t)b * NN * DD;
    const h16* Vb = VTh + (size_t)b * HH * NN + (size_t)l * NN;  // row h = l
    const int kti0 = split * (KSPLIT / 32);
    const h16* aB = adjP + ((size_t)(qt*64 + kti0) * 64 + lane) * 16;
    const int k0 = split * KSPLIT;

    // Q B-fragment: col(q)=l, k(d)=g*8+j — 16B contiguous
    const hfrag qf = *(const hfrag*)(Qb + (size_t)(q0 + l) * DD + g * 8);

    f32x16 O;
    #pragma unroll
    for (int r = 0; r < 16; ++r) O[r] = 0.f;
    float lsum = 0.f;

    const int nt = KSPLIT / 32;   // 16 iterations

    // preload iteration 0
    hfrag kf = *(const hfrag*)(Kb + (size_t)(k0 + l) * DD + g * 8);
    hfrag a0 = *(const hfrag*)(aB);
    hfrag a1 = *(const hfrag*)(aB + 8);
    hfrag v0 = *(const hfrag*)(Vb + k0 + g * 8);
    hfrag v1 = *(const hfrag*)(Vb + k0 + 16 + g * 8);

    #pragma unroll 1
    for (int it = 0; it < nt; ++it) {
        // ---- issue next-iter loads first (clamped on the tail) ----
        const int itn = (it + 1 < nt) ? it + 1 : it;
        const int ktn = k0 + itn * 32;
        const hfrag kf_n = *(const hfrag*)(Kb + (size_t)(ktn + l) * DD + g * 8);
        const hfrag a0_n = *(const hfrag*)(aB + (size_t)itn * 1024);
        const hfrag a1_n = *(const hfrag*)(aB + (size_t)itn * 1024 + 8);
        const hfrag v0_n = *(const hfrag*)(Vb + ktn + g * 8);
        const hfrag v1_n = *(const hfrag*)(Vb + ktn + 16 + g * 8);

        // ---- S = QK^T with adj folded into C ----
        f32x16 S;
        #pragma unroll
        for (int r = 0; r < 8; ++r) {
            S[r]     = (float)a0[r];
            S[8 + r] = (float)a1[r];
        }
        S = __builtin_amdgcn_mfma_f32_32x32x16_f16(kf, qf, S, 0, 0, 0);

        // ---- P = exp2(S); lane l holds P[key set][q=l] ----
        float e[16];
        #pragma unroll
        for (int r = 0; r < 16; ++r) e[r] = __builtin_amdgcn_exp2f(S[r]);
        #pragma unroll
        for (int r = 0; r < 16; ++r) lsum += e[r];

        // pack pairs: keys 8t+4g+2w+{0,1}, t=r>>2
        const unsigned W0 = pkh(e[0],  e[1]),  W1 = pkh(e[2],  e[3]);
        const unsigned W2 = pkh(e[4],  e[5]),  W3 = pkh(e[6],  e[7]);
        const unsigned W4 = pkh(e[8],  e[9]),  W5 = pkh(e[10], e[11]);
        const unsigned W6 = pkh(e[12], e[13]), W7 = pkh(e[14], e[15]);

        // exchange complementary key-halves with lane^32
        const unsigned s0 = g1 ? W0 : W2;
        const unsigned s1 = g1 ? W1 : W3;
        const unsigned s2 = g1 ? W4 : W6;
        const unsigned s3 = g1 ? W5 : W7;
        const unsigned r0 = (unsigned)__shfl_xor((int)s0, 32, 64);
        const unsigned r1 = (unsigned)__shfl_xor((int)s1, 32, 64);
        const unsigned r2 = (unsigned)__shfl_xor((int)s2, 32, 64);
        const unsigned r3 = (unsigned)__shfl_xor((int)s3, 32, 64);

        // A-fragments for PV: row(q)=l, k(key)=g*8+j
        const hfrag pa0 = g1 ? frag4(r0, r1, W2, W3) : frag4(W0, W1, r0, r1);
        const hfrag pa1 = g1 ? frag4(r2, r3, W6, W7) : frag4(W4, W5, r2, r3);

        O = __builtin_amdgcn_mfma_f32_32x32x16_f16(pa0, v0, O, 0, 0, 0);
        O = __builtin_amdgcn_mfma_f32_32x32x16_f16(pa1, v1, O, 0, 0, 0);

        kf = kf_n; a0 = a0_n; a1 = a1_n; v0 = v0_n; v1 = v1_n;
    }

    // combine the two key-half partials of each q-row
    lsum += __shfl_xor(lsum, 32, 64);

    // ---- write partials: O rows are q=(r&3)+8*(r>>2)+4g, col h=l ----
    const size_t rec = (size_t)((b * 64 + qt) * NSPLIT + split);
    if (lane < 32) lpart[rec * 32 + lane] = lsum;
    float* pb = part + rec * 1024;
    #pragma unroll
    for (int r = 0; r < 16; ++r) {
        const int q = (r & 3) + 8 * (r >> 2) + 4 * g;
        pb[q * 32 + l] = O[r];
    }
}

// ---------------------------------------------------------------------------
// Kernel 3: combine 4 split partials + temporal add + out_proj + LayerNorm.
// 4 lanes per q-row; lane jg loads split jg, computes out cols jg*8..+7.
// ---------------------------------------------------------------------------
__global__ __launch_bounds__(256) void combine_kernel(
    const float* __restrict__ part, const float* __restrict__ lpart,
    const float* __restrict__ Wbuf,
    const float* __restrict__ Wo, const float* __restrict__ bo,
    const float* __restrict__ lng, const float* __restrict__ lnb,
    float* __restrict__ out)
{
    __shared__ float sWo[HH*HH];
    __shared__ float sbo[HH], sg[HH], sb[HH];
    for (int i = threadIdx.x; i < HH*HH; i += 256) sWo[i] = Wo[i];
    if (threadIdx.x < HH) {
        sbo[threadIdx.x] = bo[threadIdx.x];
        sg[threadIdx.x]  = lng[threadIdx.x];
        sb[threadIdx.x]  = lnb[threadIdx.x];
    }
    __syncthreads();

    const int rid = blockIdx.x * 64 + (threadIdx.x >> 2);  // 0..B*N-1
    const int jg  = threadIdx.x & 3;
    const int b   = rid >> 11;
    const int qt  = (rid >> 5) & 63;
    const int qr  = rid & 31;

    const size_t rec = (size_t)((b * 64 + qt) * NSPLIT + jg);
    const float* rp = part + rec * 1024 + qr * 32;
    float o[HH];
    #pragma unroll
    for (int i = 0; i < 8; ++i) {
        float4 v = *(const float4*)(rp + i*4);
        o[4*i+0] = v.x; o[4*i+1] = v.y; o[4*i+2] = v.z; o[4*i+3] = v.w;
    }
    float lsum = lpart[rec * 32 + qr];
    lsum += __shfl_xor(lsum, 1, 64);
    lsum += __shfl_xor(lsum, 2, 64);
    #pragma unroll
    for (int c = 0; c < HH; ++c) {
        o[c] += __shfl_xor(o[c], 1, 64);
        o[c] += __shfl_xor(o[c], 2, 64);
    }

    const float wgt = Wbuf[rid] * 0.1f;
    const float inv = 1.f / lsum;
    float pr[HH];
    #pragma unroll
    for (int c = 0; c < HH; ++c) pr[c] = fmaf(o[c], inv, wgt);

    float acc[8];
    #pragma unroll
    for (int j = 0; j < 8; ++j) acc[j] = sbo[jg*8 + j];
    #pragma unroll
    for (int h = 0; h < HH; ++h) {
        #pragma unroll
        for (int j = 0; j < 8; ++j)
            acc[j] = fmaf(pr[h], sWo[h*HH + jg*8 + j], acc[j]);
    }

    float ss = 0.f, sq = 0.f;
    #pragma unroll
    for (int j = 0; j < 8; ++j) { ss += acc[j]; sq += acc[j]*acc[j]; }
    ss += __shfl_xor(ss, 1, 64); ss += __shfl_xor(ss, 2, 64);
    sq += __shfl_xor(sq, 1, 64); sq += __shfl_xor(sq, 2, 64);
    const float mean = ss * (1.f / HH);
    const float var  = sq * (1.f / HH) - mean * mean;
    const float rstd = rsqrtf(var + 1e-5f);

    float res[8];
    #pragma unroll
    for (int j = 0; j < 8; ++j)
        res[j] = (acc[j] - mean) * rstd * sg[jg*8 + j] + sb[jg*8 + j];

    float* op = out + (size_t)rid * HH + jg * 8;
    *(float4*)(op)     = make_float4(res[0], res[1], res[2], res[3]);
    *(float4*)(op + 4) = make_float4(res[4], res[5], res[6], res[7]);
}

// ---------------------------------------------------------------------------
extern "C" void kernel_launch(void* const* d_in, const int* in_sizes, int n_in,
                              void* d_out, int out_size, void* d_ws, size_t ws_size,
                              hipStream_t stream)
{
    const float* x    = (const float*)d_in[0];
    const float* feat = (const float*)d_in[1];
    const float* adj  = (const float*)d_in[2];
    const float* dlw  = (const float*)d_in[3];
    const float* aw   = (const float*)d_in[4];
    const float* Wk   = (const float*)d_in[5];
    const float* bk   = (const float*)d_in[6];
    const float* Wq   = (const float*)d_in[7];
    const float* bq   = (const float*)d_in[8];
    const float* Wv   = (const float*)d_in[9];
    const float* bv   = (const float*)d_in[10];
    const float* Wo   = (const float*)d_in[11];
    const float* bo   = (const float*)d_in[12];
    const float* lng  = (const float*)d_in[13];
    const float* lnb  = (const float*)d_in[14];

    h16* Qh   = (h16*)d_ws;                     // 524288 h16 (1 MB)
    h16* Kh   = Qh + 524288;                    // 1 MB
    h16* VTh  = Kh + 524288;                    // 1048576 h16 (2 MB)
    float* Wb = (float*)(VTh + 1048576);        // 32768 f32 (128 KB)
    h16* adjP = (h16*)(Wb + 32768);             // NN*NN h16 (8 MB), packed
    float* part  = (float*)(adjP + (size_t)NN*NN);  // 16*64*4*1024 f32 (16 MB)
    float* lpart = part + 4194304;              // 131072 f32 (512 KB)
    float* out = (float*)d_out;

    proj_kernel<<<(BB*NN)/256, 256, 0, stream>>>(x, feat, dlw, aw, Wk, bk, Wq, bq,
                                                 Wv, bv, Qh, Kh, VTh, Wb);
    adjp_kernel<<<dim3(64, 16), 256, 0, stream>>>(adj, aw, adjP);
    attn_kernel<<<64*4*NSPLIT, 256, 0, stream>>>(Qh, Kh, VTh, adjP, part, lpart);
    combine_kernel<<<(BB*NN)/64, 256, 0, stream>>>(part, lpart, Wb, Wo, bo,
                                                   lng, lnb, out);
}

// Round 8
// 53.615 us; speedup vs baseline: 2.2333x; 1.0897x over previous
//
#include <hip/hip_runtime.h>
#include <hip/hip_bf16.h>
#include <hip/hip_fp16.h>

// Problem constants
#define BB 16
#define TT 64
#define NN 2048
#define HH 32
#define DD 16
#define LAG 7
#define NSPLIT 4
#define KSPLIT (NN / NSPLIT)   // 512 keys per wave
#define LOG2E 1.44269504088896f

typedef _Float16 h16;
typedef __attribute__((ext_vector_type(8))) _Float16 hfrag;
typedef __attribute__((ext_vector_type(2))) __fp16 fp16x2;
typedef __attribute__((ext_vector_type(16))) float f32x16;

static __device__ __forceinline__ unsigned pkh(float a, float b) {
    union { fp16x2 h; unsigned u; } x;
    x.h = __builtin_amdgcn_cvt_pkrtz(a, b);
    return x.u;
}
static __device__ __forceinline__ hfrag frag4(unsigned w0, unsigned w1,
                                              unsigned w2, unsigned w3) {
    union { unsigned u[4]; hfrag h; } x;
    x.u[0] = w0; x.u[1] = w1; x.u[2] = w2; x.u[3] = w3;
    return x.h;
}

// ---------------------------------------------------------------------------
// Kernel 1: projections, wave-specialized to keep per-thread state small
// (round-7 profile: monolithic version got 60 VGPRs for ~96 live floats ->
// scratch thrash at 1 wave/SIMD, 41 us, VALUBusy 3%).
// Block = 4 waves x 64 rows. wave0: Q (prescaled); wave1: K + temporal;
// wave2/3: V columns 0-15 / 16-31. Q,K row-major fp16 [b][n][16];
// V^T fp16 [b][h][n]; temporal term f32.
// ---------------------------------------------------------------------------
__global__ __launch_bounds__(256) void proj_kernel(
    const float* __restrict__ x, const float* __restrict__ feat,
    const float* __restrict__ dlw, const float* __restrict__ awp,
    const float* __restrict__ Wk, const float* __restrict__ bk,
    const float* __restrict__ Wq, const float* __restrict__ bq,
    const float* __restrict__ Wv, const float* __restrict__ bv,
    h16* __restrict__ Qh, h16* __restrict__ Kh, h16* __restrict__ VTh,
    float* __restrict__ Wbuf)
{
    __shared__ float sWk[HH*DD], sWq[HH*DD], sWv[HH*HH];
    for (int i = threadIdx.x; i < HH*DD; i += 256) { sWk[i] = Wk[i]; sWq[i] = Wq[i]; }
    for (int i = threadIdx.x; i < HH*HH; i += 256) sWv[i] = Wv[i];
    __syncthreads();

    const int wid  = threadIdx.x >> 6;    // 0..3: q / k+temporal / v-lo / v-hi
    const int lane = threadIdx.x & 63;
    const int rid  = blockIdx.x * 64 + lane;   // 0 .. B*N-1
    const int b = rid >> 11;
    const int n = rid & (NN - 1);

    // load feature row [32] (4 waves duplicate-read the same rows; L1-hot)
    float f[HH];
    {
        const float4* fp = (const float4*)(feat + (size_t)rid * HH);
        #pragma unroll
        for (int i = 0; i < 8; ++i) {
            float4 v = fp[i];
            f[4*i+0] = v.x; f[4*i+1] = v.y; f[4*i+2] = v.z; f[4*i+3] = v.w;
        }
    }

    if (wid == 0) {
        // ---- Q, prescaled by (1-blend)*0.25*log2e ----
        const float blend = 1.f / (1.f + __expf(-awp[0]));
        const float qscale = (1.f - blend) * 0.25f * LOG2E;
        float qa[DD];
        #pragma unroll
        for (int d = 0; d < DD; ++d) qa[d] = bq[d];
        #pragma unroll
        for (int h = 0; h < HH; ++h) {
            const float fh = f[h];
            #pragma unroll
            for (int d = 0; d < DD; ++d) qa[d] += fh * sWq[h*DD + d];
        }
        hfrag q0, q1;
        #pragma unroll
        for (int i = 0; i < 8; ++i) {
            q0[i] = (h16)(qa[i] * qscale);
            q1[i] = (h16)(qa[8+i] * qscale);
        }
        *(hfrag*)(Qh + (size_t)rid * DD)     = q0;
        *(hfrag*)(Qh + (size_t)rid * DD + 8) = q1;
    } else if (wid == 1) {
        // ---- K ----
        float ka[DD];
        #pragma unroll
        for (int d = 0; d < DD; ++d) ka[d] = bk[d];
        #pragma unroll
        for (int h = 0; h < HH; ++h) {
            const float fh = f[h];
            #pragma unroll
            for (int d = 0; d < DD; ++d) ka[d] += fh * sWk[h*DD + d];
        }
        hfrag k0, k1;
        #pragma unroll
        for (int i = 0; i < 8; ++i) { k0[i] = (h16)ka[i]; k1[i] = (h16)ka[8+i]; }
        *(hfrag*)(Kh + (size_t)rid * DD)     = k0;
        *(hfrag*)(Kh + (size_t)rid * DD + 8) = k1;

        // ---- temporal delay-weighted sum ----
        float w[LAG];
        float mx = dlw[0];
        #pragma unroll
        for (int t = 1; t < LAG; ++t) mx = fmaxf(mx, dlw[t]);
        float sum = 0.f;
        #pragma unroll
        for (int t = 0; t < LAG; ++t) { w[t] = __expf(dlw[t] - mx); sum += w[t]; }
        const float inv = 1.f / sum;
        float acc = 0.f;
        #pragma unroll
        for (int t = 0; t < LAG; ++t)
            acc += w[t] * inv * x[(size_t)b * TT * NN + (size_t)(TT - 1 - t) * NN + n];
        Wbuf[rid] = acc;
    } else {
        // ---- V columns j0..j0+15, stored transposed [b][h][n] ----
        const int j0 = (wid - 2) * 16;
        float va[16];
        #pragma unroll
        for (int j = 0; j < 16; ++j) va[j] = bv[j0 + j];
        #pragma unroll
        for (int h = 0; h < HH; ++h) {
            const float fh = f[h];
            #pragma unroll
            for (int j = 0; j < 16; ++j) va[j] += fh * sWv[h*HH + j0 + j];
        }
        h16* vb = VTh + (size_t)b * HH * NN + n;
        #pragma unroll
        for (int j = 0; j < 16; ++j) vb[(size_t)(j0 + j) * NN] = (h16)va[j];
    }
}

// ---------------------------------------------------------------------------
// Kernel 1b: pack adj into MFMA C-fragment order, scaled by blend*log2e:
//   adjP[((qt*64 + kti)*64 + lane)*16 + r] = sc * adj[qt*32 + (lane&31)]
//                                               [kti*32 + key(r, lane>>5)]
// where key(r,g) = (r&3) + 8*(r>>2) + 4*g  (32x32x16 C-layout, m74/m101).
// Per-lane 32B contiguous -> attn reads 2 coalesced b128 per 32-key tile.
// ---------------------------------------------------------------------------
__global__ __launch_bounds__(256) void adjp_kernel(
    const float* __restrict__ adj, const float* __restrict__ awp,
    h16* __restrict__ adjP)
{
    __shared__ float s[32][129];
    const float blend = 1.f / (1.f + __expf(-awp[0]));
    const float sc = blend * LOG2E;
    const int qt = blockIdx.x;        // 0..63
    const int kg = blockIdx.y;        // 0..15 (128-key group)
    const int t  = threadIdx.x;

    const int row = t >> 3;           // 0..31
    const int qd  = t & 7;            // 0..7
    const float* ap = adj + (size_t)(qt*32 + row)*NN + kg*128 + qd*16;
    #pragma unroll
    for (int i = 0; i < 4; ++i) {
        const float4 v = *(const float4*)(ap + i*4);
        s[row][qd*16 + i*4 + 0] = v.x;
        s[row][qd*16 + i*4 + 1] = v.y;
        s[row][qd*16 + i*4 + 2] = v.z;
        s[row][qd*16 + i*4 + 3] = v.w;
    }
    __syncthreads();

    const int kl   = t >> 6;          // 0..3 local ktile
    const int lane = t & 63;
    const int l = lane & 31, g = lane >> 5;
    hfrag o0, o1;
    #pragma unroll
    for (int r = 0; r < 8; ++r) {
        const int k0 = (r & 3) + 8 * (r >> 2) + 4 * g;
        const int k1 = ((r+8) & 3) + 8 * ((r+8) >> 2) + 4 * g;
        o0[r] = (h16)(sc * s[l][kl*32 + k0]);
        o1[r] = (h16)(sc * s[l][kl*32 + k1]);
    }
    h16* op = adjP + ((size_t)((qt*64 + kg*4 + kl)*64) + lane) * 16;
    *(hfrag*)(op)     = o0;
    *(hfrag*)(op + 8) = o1;
}

// ---------------------------------------------------------------------------
// Kernel 2: split-K attention, 32x32x16 MFMA, swapped operands, zero LDS,
// 1-deep register prefetch of K/adjP/V fragments (hides L2/L3 latency).
//   S = mfma(A=K_tile, B=Q_scaled, C=cvt(adjP))   [no-max softmax: |S|<~4]
//   P = exp2(S); C->A fix-up via cvt_pkrtz + shfl_xor(32); O += mfma(P,V,O).
// Grid: 64 qt x 4 bg x 4 split = 1024 blocks x 4 waves (wave = batch).
// ---------------------------------------------------------------------------
__global__ __launch_bounds__(256, 4) void attn_kernel(
    const h16* __restrict__ Qh, const h16* __restrict__ Kh,
    const h16* __restrict__ VTh, const h16* __restrict__ adjP,
    float* __restrict__ part, float* __restrict__ lpart)
{
    const int id    = blockIdx.x;         // qt(64) x bg(4) x split(4)
    const int qt    = id >> 4;
    const int bg    = (id >> 2) & 3;
    const int split = id & 3;
    const int wave  = threadIdx.x >> 6;
    const int lane  = threadIdx.x & 63;
    const int b     = bg * 4 + wave;
    const int q0    = qt * 32;
    const int l = lane & 31, g = lane >> 5;
    const bool g1 = (g != 0);

    const h16* Qb = Qh + (size_t)b * NN * DD;
    const h16* Kb = Kh + (size_t)b * NN * DD;
    const h16* Vb = VTh + (size_t)b * HH * NN + (size_t)l * NN;  // row h = l
    const int kti0 = split * (KSPLIT / 32);
    const h16* aB = adjP + ((size_t)(qt*64 + kti0) * 64 + lane) * 16;
    const int k0 = split * KSPLIT;

    // Q B-fragment: col(q)=l, k(d)=g*8+j — 16B contiguous
    const hfrag qf = *(const hfrag*)(Qb + (size_t)(q0 + l) * DD + g * 8);

    f32x16 O;
    #pragma unroll
    for (int r = 0; r < 16; ++r) O[r] = 0.f;
    float lsum = 0.f;

    const int nt = KSPLIT / 32;   // 16 iterations

    // preload iteration 0
    hfrag kf = *(const hfrag*)(Kb + (size_t)(k0 + l) * DD + g * 8);
    hfrag a0 = *(const hfrag*)(aB);
    hfrag a1 = *(const hfrag*)(aB + 8);
    hfrag v0 = *(const hfrag*)(Vb + k0 + g * 8);
    hfrag v1 = *(const hfrag*)(Vb + k0 + 16 + g * 8);

    #pragma unroll 1
    for (int it = 0; it < nt; ++it) {
        // ---- issue next-iter loads first (clamped on the tail) ----
        const int itn = (it + 1 < nt) ? it + 1 : it;
        const int ktn = k0 + itn * 32;
        const hfrag kf_n = *(const hfrag*)(Kb + (size_t)(ktn + l) * DD + g * 8);
        const hfrag a0_n = *(const hfrag*)(aB + (size_t)itn * 1024);
        const hfrag a1_n = *(const hfrag*)(aB + (size_t)itn * 1024 + 8);
        const hfrag v0_n = *(const hfrag*)(Vb + ktn + g * 8);
        const hfrag v1_n = *(const hfrag*)(Vb + ktn + 16 + g * 8);

        // ---- S = QK^T with adj folded into C ----
        f32x16 S;
        #pragma unroll
        for (int r = 0; r < 8; ++r) {
            S[r]     = (float)a0[r];
            S[8 + r] = (float)a1[r];
        }
        S = __builtin_amdgcn_mfma_f32_32x32x16_f16(kf, qf, S, 0, 0, 0);

        // ---- P = exp2(S); lane l holds P[key set][q=l] ----
        float e[16];
        #pragma unroll
        for (int r = 0; r < 16; ++r) e[r] = __builtin_amdgcn_exp2f(S[r]);
        #pragma unroll
        for (int r = 0; r < 16; ++r) lsum += e[r];

        // pack pairs: keys 8t+4g+2w+{0,1}, t=r>>2
        const unsigned W0 = pkh(e[0],  e[1]),  W1 = pkh(e[2],  e[3]);
        const unsigned W2 = pkh(e[4],  e[5]),  W3 = pkh(e[6],  e[7]);
        const unsigned W4 = pkh(e[8],  e[9]),  W5 = pkh(e[10], e[11]);
        const unsigned W6 = pkh(e[12], e[13]), W7 = pkh(e[14], e[15]);

        // exchange complementary key-halves with lane^32
        const unsigned s0 = g1 ? W0 : W2;
        const unsigned s1 = g1 ? W1 : W3;
        const unsigned s2 = g1 ? W4 : W6;
        const unsigned s3 = g1 ? W5 : W7;
        const unsigned r0 = (unsigned)__shfl_xor((int)s0, 32, 64);
        const unsigned r1 = (unsigned)__shfl_xor((int)s1, 32, 64);
        const unsigned r2 = (unsigned)__shfl_xor((int)s2, 32, 64);
        const unsigned r3 = (unsigned)__shfl_xor((int)s3, 32, 64);

        // A-fragments for PV: row(q)=l, k(key)=g*8+j
        const hfrag pa0 = g1 ? frag4(r0, r1, W2, W3) : frag4(W0, W1, r0, r1);
        const hfrag pa1 = g1 ? frag4(r2, r3, W6, W7) : frag4(W4, W5, r2, r3);

        O = __builtin_amdgcn_mfma_f32_32x32x16_f16(pa0, v0, O, 0, 0, 0);
        O = __builtin_amdgcn_mfma_f32_32x32x16_f16(pa1, v1, O, 0, 0, 0);

        kf = kf_n; a0 = a0_n; a1 = a1_n; v0 = v0_n; v1 = v1_n;
    }

    // combine the two key-half partials of each q-row
    lsum += __shfl_xor(lsum, 32, 64);

    // ---- write partials: O rows are q=(r&3)+8*(r>>2)+4g, col h=l ----
    const size_t rec = (size_t)((b * 64 + qt) * NSPLIT + split);
    if (lane < 32) lpart[rec * 32 + lane] = lsum;
    float* pb = part + rec * 1024;
    #pragma unroll
    for (int r = 0; r < 16; ++r) {
        const int q = (r & 3) + 8 * (r >> 2) + 4 * g;
        pb[q * 32 + l] = O[r];
    }
}

// ---------------------------------------------------------------------------
// Kernel 3: combine 4 split partials + temporal add + out_proj + LayerNorm.
// 4 lanes per q-row; lane jg loads split jg, computes out cols jg*8..+7.
// ---------------------------------------------------------------------------
__global__ __launch_bounds__(256) void combine_kernel(
    const float* __restrict__ part, const float* __restrict__ lpart,
    const float* __restrict__ Wbuf,
    const float* __restrict__ Wo, const float* __restrict__ bo,
    const float* __restrict__ lng, const float* __restrict__ lnb,
    float* __restrict__ out)
{
    __shared__ float sWo[HH*HH];
    __shared__ float sbo[HH], sg[HH], sb[HH];
    for (int i = threadIdx.x; i < HH*HH; i += 256) sWo[i] = Wo[i];
    if (threadIdx.x < HH) {
        sbo[threadIdx.x] = bo[threadIdx.x];
        sg[threadIdx.x]  = lng[threadIdx.x];
        sb[threadIdx.x]  = lnb[threadIdx.x];
    }
    __syncthreads();

    const int rid = blockIdx.x * 64 + (threadIdx.x >> 2);  // 0..B*N-1
    const int jg  = threadIdx.x & 3;
    const int b   = rid >> 11;
    const int qt  = (rid >> 5) & 63;
    const int qr  = rid & 31;

    const size_t rec = (size_t)((b * 64 + qt) * NSPLIT + jg);
    const float* rp = part + rec * 1024 + qr * 32;
    float o[HH];
    #pragma unroll
    for (int i = 0; i < 8; ++i) {
        float4 v = *(const float4*)(rp + i*4);
        o[4*i+0] = v.x; o[4*i+1] = v.y; o[4*i+2] = v.z; o[4*i+3] = v.w;
    }
    float lsum = lpart[rec * 32 + qr];
    lsum += __shfl_xor(lsum, 1, 64);
    lsum += __shfl_xor(lsum, 2, 64);
    #pragma unroll
    for (int c = 0; c < HH; ++c) {
        o[c] += __shfl_xor(o[c], 1, 64);
        o[c] += __shfl_xor(o[c], 2, 64);
    }

    const float wgt = Wbuf[rid] * 0.1f;
    const float inv = 1.f / lsum;
    float pr[HH];
    #pragma unroll
    for (int c = 0; c < HH; ++c) pr[c] = fmaf(o[c], inv, wgt);

    float acc[8];
    #pragma unroll
    for (int j = 0; j < 8; ++j) acc[j] = sbo[jg*8 + j];
    #pragma unroll
    for (int h = 0; h < HH; ++h) {
        #pragma unroll
        for (int j = 0; j < 8; ++j)
            acc[j] = fmaf(pr[h], sWo[h*HH + jg*8 + j], acc[j]);
    }

    float ss = 0.f, sq = 0.f;
    #pragma unroll
    for (int j = 0; j < 8; ++j) { ss += acc[j]; sq += acc[j]*acc[j]; }
    ss += __shfl_xor(ss, 1, 64); ss += __shfl_xor(ss, 2, 64);
    sq += __shfl_xor(sq, 1, 64); sq += __shfl_xor(sq, 2, 64);
    const float mean = ss * (1.f / HH);
    const float var  = sq * (1.f / HH) - mean * mean;
    const float rstd = rsqrtf(var + 1e-5f);

    float res[8];
    #pragma unroll
    for (int j = 0; j < 8; ++j)
        res[j] = (acc[j] - mean) * rstd * sg[jg*8 + j] + sb[jg*8 + j];

    float* op = out + (size_t)rid * HH + jg * 8;
    *(float4*)(op)     = make_float4(res[0], res[1], res[2], res[3]);
    *(float4*)(op + 4) = make_float4(res[4], res[5], res[6], res[7]);
}

// ---------------------------------------------------------------------------
extern "C" void kernel_launch(void* const* d_in, const int* in_sizes, int n_in,
                              void* d_out, int out_size, void* d_ws, size_t ws_size,
                              hipStream_t stream)
{
    const float* x    = (const float*)d_in[0];
    const float* feat = (const float*)d_in[1];
    const float* adj  = (const float*)d_in[2];
    const float* dlw  = (const float*)d_in[3];
    const float* aw   = (const float*)d_in[4];
    const float* Wk   = (const float*)d_in[5];
    const float* bk   = (const float*)d_in[6];
    const float* Wq   = (const float*)d_in[7];
    const float* bq   = (const float*)d_in[8];
    const float* Wv   = (const float*)d_in[9];
    const float* bv   = (const float*)d_in[10];
    const float* Wo   = (const float*)d_in[11];
    const float* bo   = (const float*)d_in[12];
    const float* lng  = (const float*)d_in[13];
    const float* lnb  = (const float*)d_in[14];

    h16* Qh   = (h16*)d_ws;                     // 524288 h16 (1 MB)
    h16* Kh   = Qh + 524288;                    // 1 MB
    h16* VTh  = Kh + 524288;                    // 1048576 h16 (2 MB)
    float* Wb = (float*)(VTh + 1048576);        // 32768 f32 (128 KB)
    h16* adjP = (h16*)(Wb + 32768);             // NN*NN h16 (8 MB), packed
    float* part  = (float*)(adjP + (size_t)NN*NN);  // 16*64*4*1024 f32 (16 MB)
    float* lpart = part + 4194304;              // 131072 f32 (512 KB)
    float* out = (float*)d_out;

    proj_kernel<<<(BB*NN)/64, 256, 0, stream>>>(x, feat, dlw, aw, Wk, bk, Wq, bq,
                                                Wv, bv, Qh, Kh, VTh, Wb);
    adjp_kernel<<<dim3(64, 16), 256, 0, stream>>>(adj, aw, adjP);
    attn_kernel<<<64*4*NSPLIT, 256, 0, stream>>>(Qh, Kh, VTh, adjP, part, lpart);
    combine_kernel<<<(BB*NN)/64, 256, 0, stream>>>(part, lpart, Wb, Wo, bo,
                                                   lng, lnb, out);
}

// Round 9
// 42.108 us; speedup vs baseline: 2.8436x; 1.2733x over previous
//
#include <hip/hip_runtime.h>
#include <hip/hip_bf16.h>
#include <hip/hip_fp16.h>

// Problem constants
#define BB 16
#define TT 64
#define NN 2048
#define HH 32
#define DD 16
#define LAG 7
#define NSPLIT 4
#define KSPLIT (NN / NSPLIT)   // 512 keys per wave
#define LOG2E 1.44269504088896f

typedef _Float16 h16;
typedef __attribute__((ext_vector_type(8))) _Float16 hfrag;
typedef __attribute__((ext_vector_type(2))) __fp16 fp16x2;
typedef __attribute__((ext_vector_type(16))) float f32x16;

static __device__ __forceinline__ unsigned pkh(float a, float b) {
    union { fp16x2 h; unsigned u; } x;
    x.h = __builtin_amdgcn_cvt_pkrtz(a, b);
    return x.u;
}
static __device__ __forceinline__ hfrag frag4(unsigned w0, unsigned w1,
                                              unsigned w2, unsigned w3) {
    union { unsigned u[4]; hfrag h; } x;
    x.u[0] = w0; x.u[1] = w1; x.u[2] = w2; x.u[3] = w3;
    return x.h;
}

// ---------------------------------------------------------------------------
// Kernel 1 (prep): blocks 0..511 = projections (wave-specialized);
// blocks 512..1535 = adj pack. Independent work fused to cut a launch gap.
//
// proj: block = 4 waves x 64 rows. wave0: Q prescaled by (1-blend)*0.25*log2e;
// wave1: K + temporal term; wave2/3: V columns 0-15 / 16-31 (transposed store).
// adjp: pack adj into MFMA C-fragment order scaled by blend*log2e:
//   adjP[((qt*64+kti)*64+lane)*16 + r] = sc*adj[qt*32+(lane&31)][kti*32+key]
//   key(r,g) = (r&3)+8*(r>>2)+4*g   (32x32x16 C-layout, m74/m101)
// ---------------------------------------------------------------------------
__global__ __launch_bounds__(256) void prep_kernel(
    const float* __restrict__ x, const float* __restrict__ feat,
    const float* __restrict__ dlw, const float* __restrict__ awp,
    const float* __restrict__ Wk, const float* __restrict__ bk,
    const float* __restrict__ Wq, const float* __restrict__ bq,
    const float* __restrict__ Wv, const float* __restrict__ bv,
    const float* __restrict__ adj,
    h16* __restrict__ Qh, h16* __restrict__ Kh, h16* __restrict__ VTh,
    h16* __restrict__ adjP, float* __restrict__ Wbuf)
{
    __shared__ __attribute__((aligned(16))) float smem[4228];

    if (blockIdx.x < 512) {
        // ================= proj =================
        float* sWk = smem;           // 512
        float* sWq = smem + 512;     // 512
        float* sWv = smem + 1024;    // 1024
        for (int i = threadIdx.x; i < HH*DD; i += 256) { sWk[i] = Wk[i]; sWq[i] = Wq[i]; }
        for (int i = threadIdx.x; i < HH*HH; i += 256) sWv[i] = Wv[i];
        __syncthreads();

        const int wid  = threadIdx.x >> 6;    // 0..3
        const int lane = threadIdx.x & 63;
        const int rid  = blockIdx.x * 64 + lane;   // 0 .. B*N-1
        const int b = rid >> 11;
        const int n = rid & (NN - 1);

        float f[HH];
        {
            const float4* fp = (const float4*)(feat + (size_t)rid * HH);
            #pragma unroll
            for (int i = 0; i < 8; ++i) {
                float4 v = fp[i];
                f[4*i+0] = v.x; f[4*i+1] = v.y; f[4*i+2] = v.z; f[4*i+3] = v.w;
            }
        }

        if (wid == 0) {
            const float blend = 1.f / (1.f + __expf(-awp[0]));
            const float qscale = (1.f - blend) * 0.25f * LOG2E;
            float qa[DD];
            #pragma unroll
            for (int d = 0; d < DD; ++d) qa[d] = bq[d];
            #pragma unroll
            for (int h = 0; h < HH; ++h) {
                const float fh = f[h];
                #pragma unroll
                for (int d = 0; d < DD; ++d) qa[d] += fh * sWq[h*DD + d];
            }
            hfrag q0, q1;
            #pragma unroll
            for (int i = 0; i < 8; ++i) {
                q0[i] = (h16)(qa[i] * qscale);
                q1[i] = (h16)(qa[8+i] * qscale);
            }
            *(hfrag*)(Qh + (size_t)rid * DD)     = q0;
            *(hfrag*)(Qh + (size_t)rid * DD + 8) = q1;
        } else if (wid == 1) {
            float ka[DD];
            #pragma unroll
            for (int d = 0; d < DD; ++d) ka[d] = bk[d];
            #pragma unroll
            for (int h = 0; h < HH; ++h) {
                const float fh = f[h];
                #pragma unroll
                for (int d = 0; d < DD; ++d) ka[d] += fh * sWk[h*DD + d];
            }
            hfrag k0, k1;
            #pragma unroll
            for (int i = 0; i < 8; ++i) { k0[i] = (h16)ka[i]; k1[i] = (h16)ka[8+i]; }
            *(hfrag*)(Kh + (size_t)rid * DD)     = k0;
            *(hfrag*)(Kh + (size_t)rid * DD + 8) = k1;

            float w[LAG];
            float mx = dlw[0];
            #pragma unroll
            for (int t = 1; t < LAG; ++t) mx = fmaxf(mx, dlw[t]);
            float sum = 0.f;
            #pragma unroll
            for (int t = 0; t < LAG; ++t) { w[t] = __expf(dlw[t] - mx); sum += w[t]; }
            const float inv = 1.f / sum;
            float acc = 0.f;
            #pragma unroll
            for (int t = 0; t < LAG; ++t)
                acc += w[t] * inv * x[(size_t)b * TT * NN + (size_t)(TT - 1 - t) * NN + n];
            Wbuf[rid] = acc;
        } else {
            const int j0 = (wid - 2) * 16;
            float va[16];
            #pragma unroll
            for (int j = 0; j < 16; ++j) va[j] = bv[j0 + j];
            #pragma unroll
            for (int h = 0; h < HH; ++h) {
                const float fh = f[h];
                #pragma unroll
                for (int j = 0; j < 16; ++j) va[j] += fh * sWv[h*HH + j0 + j];
            }
            h16* vb = VTh + (size_t)b * HH * NN + n;
            #pragma unroll
            for (int j = 0; j < 16; ++j) vb[(size_t)(j0 + j) * NN] = (h16)va[j];
        }
    } else {
        // ================= adjp =================
        float* s = smem;                  // [32][129] flattened
        const float blend = 1.f / (1.f + __expf(-awp[0]));
        const float sc = blend * LOG2E;
        const int id = blockIdx.x - 512;
        const int qt = id >> 4;           // 0..63
        const int kg = id & 15;           // 0..15 (128-key group)
        const int t  = threadIdx.x;

        const int row = t >> 3;           // 0..31
        const int qd  = t & 7;            // 0..7
        const float* ap = adj + (size_t)(qt*32 + row)*NN + kg*128 + qd*16;
        #pragma unroll
        for (int i = 0; i < 4; ++i) {
            const float4 v = *(const float4*)(ap + i*4);
            s[row*129 + qd*16 + i*4 + 0] = v.x;
            s[row*129 + qd*16 + i*4 + 1] = v.y;
            s[row*129 + qd*16 + i*4 + 2] = v.z;
            s[row*129 + qd*16 + i*4 + 3] = v.w;
        }
        __syncthreads();

        const int kl   = t >> 6;          // 0..3 local ktile
        const int lane = t & 63;
        const int l = lane & 31, g = lane >> 5;
        hfrag o0, o1;
        #pragma unroll
        for (int r = 0; r < 8; ++r) {
            const int k0 = (r & 3) + 8 * (r >> 2) + 4 * g;
            const int k1 = ((r+8) & 3) + 8 * ((r+8) >> 2) + 4 * g;
            o0[r] = (h16)(sc * s[l*129 + kl*32 + k0]);
            o1[r] = (h16)(sc * s[l*129 + kl*32 + k1]);
        }
        h16* op = adjP + ((size_t)((qt*64 + kg*4 + kl)*64) + lane) * 16;
        *(hfrag*)(op)     = o0;
        *(hfrag*)(op + 8) = o1;
    }
}

// ---------------------------------------------------------------------------
// Kernel 2: fused split-K attention + combine + out_proj + LayerNorm.
// Block = (qt, b): 4 waves, wave = split (512 keys each). Main loop identical
// to round-8 (32x32x16 MFMA, swapped operands, adj-in-C, 1-deep prefetch,
// no-max softmax). Partials go to LDS (not global); one __syncthreads; then
// in-block cross-split reduce + Wo GEMM + LN. Eliminates the 32 MB part
// round-trip and the combine kernel.
// ---------------------------------------------------------------------------
__global__ __launch_bounds__(256, 4) void attn_kernel(
    const h16* __restrict__ Qh, const h16* __restrict__ Kh,
    const h16* __restrict__ VTh, const h16* __restrict__ adjP,
    const float* __restrict__ Wbuf,
    const float* __restrict__ Wo, const float* __restrict__ bo,
    const float* __restrict__ lng, const float* __restrict__ lnb,
    float* __restrict__ out)
{
    const int qt    = blockIdx.x >> 4;    // 0..63
    const int b     = blockIdx.x & 15;    // 0..15
    const int wave  = threadIdx.x >> 6;   // = split
    const int lane  = threadIdx.x & 63;
    const int split = wave;
    const int q0    = qt * 32;
    const int l = lane & 31, g = lane >> 5;
    const bool g1 = (g != 0);

    __shared__ __attribute__((aligned(16))) float Os[4][32][36];  // pad 36: 16B rows, conflict-free
    __shared__ float Ls[4][32];
    __shared__ float sWo[HH*HH];

    for (int i = threadIdx.x; i < HH*HH; i += 256) sWo[i] = Wo[i];

    const h16* Qb = Qh + (size_t)b * NN * DD;
    const h16* Kb = Kh + (size_t)b * NN * DD;
    const h16* Vb = VTh + (size_t)b * HH * NN + (size_t)l * NN;  // row h = l
    const int kti0 = split * (KSPLIT / 32);
    const h16* aB = adjP + ((size_t)(qt*64 + kti0) * 64 + lane) * 16;
    const int k0 = split * KSPLIT;

    // Q B-fragment: col(q)=l, k(d)=g*8+j — 16B contiguous
    const hfrag qf = *(const hfrag*)(Qb + (size_t)(q0 + l) * DD + g * 8);

    f32x16 O;
    #pragma unroll
    for (int r = 0; r < 16; ++r) O[r] = 0.f;
    float lsum = 0.f;

    const int nt = KSPLIT / 32;   // 16 iterations

    // preload iteration 0
    hfrag kf = *(const hfrag*)(Kb + (size_t)(k0 + l) * DD + g * 8);
    hfrag a0 = *(const hfrag*)(aB);
    hfrag a1 = *(const hfrag*)(aB + 8);
    hfrag v0 = *(const hfrag*)(Vb + k0 + g * 8);
    hfrag v1 = *(const hfrag*)(Vb + k0 + 16 + g * 8);

    #pragma unroll 1
    for (int it = 0; it < nt; ++it) {
        // ---- issue next-iter loads first (clamped on the tail) ----
        const int itn = (it + 1 < nt) ? it + 1 : it;
        const int ktn = k0 + itn * 32;
        const hfrag kf_n = *(const hfrag*)(Kb + (size_t)(ktn + l) * DD + g * 8);
        const hfrag a0_n = *(const hfrag*)(aB + (size_t)itn * 1024);
        const hfrag a1_n = *(const hfrag*)(aB + (size_t)itn * 1024 + 8);
        const hfrag v0_n = *(const hfrag*)(Vb + ktn + g * 8);
        const hfrag v1_n = *(const hfrag*)(Vb + ktn + 16 + g * 8);

        // ---- S = QK^T with adj folded into C ----
        f32x16 S;
        #pragma unroll
        for (int r = 0; r < 8; ++r) {
            S[r]     = (float)a0[r];
            S[8 + r] = (float)a1[r];
        }
        S = __builtin_amdgcn_mfma_f32_32x32x16_f16(kf, qf, S, 0, 0, 0);

        // ---- P = exp2(S); lane l holds P[key set][q=l] ----
        float e[16];
        #pragma unroll
        for (int r = 0; r < 16; ++r) e[r] = __builtin_amdgcn_exp2f(S[r]);
        #pragma unroll
        for (int r = 0; r < 16; ++r) lsum += e[r];

        // pack pairs: keys 8t+4g+2w+{0,1}, t=r>>2
        const unsigned W0 = pkh(e[0],  e[1]),  W1 = pkh(e[2],  e[3]);
        const unsigned W2 = pkh(e[4],  e[5]),  W3 = pkh(e[6],  e[7]);
        const unsigned W4 = pkh(e[8],  e[9]),  W5 = pkh(e[10], e[11]);
        const unsigned W6 = pkh(e[12], e[13]), W7 = pkh(e[14], e[15]);

        // exchange complementary key-halves with lane^32
        const unsigned s0 = g1 ? W0 : W2;
        const unsigned s1 = g1 ? W1 : W3;
        const unsigned s2 = g1 ? W4 : W6;
        const unsigned s3 = g1 ? W5 : W7;
        const unsigned r0 = (unsigned)__shfl_xor((int)s0, 32, 64);
        const unsigned r1 = (unsigned)__shfl_xor((int)s1, 32, 64);
        const unsigned r2 = (unsigned)__shfl_xor((int)s2, 32, 64);
        const unsigned r3 = (unsigned)__shfl_xor((int)s3, 32, 64);

        // A-fragments for PV: row(q)=l, k(key)=g*8+j
        const hfrag pa0 = g1 ? frag4(r0, r1, W2, W3) : frag4(W0, W1, r0, r1);
        const hfrag pa1 = g1 ? frag4(r2, r3, W6, W7) : frag4(W4, W5, r2, r3);

        O = __builtin_amdgcn_mfma_f32_32x32x16_f16(pa0, v0, O, 0, 0, 0);
        O = __builtin_amdgcn_mfma_f32_32x32x16_f16(pa1, v1, O, 0, 0, 0);

        kf = kf_n; a0 = a0_n; a1 = a1_n; v0 = v0_n; v1 = v1_n;
    }

    // combine the two key-half partials of each q-row
    lsum += __shfl_xor(lsum, 32, 64);

    // ---- stage partials to LDS ----
    if (lane < 32) Ls[wave][lane] = lsum;
    #pragma unroll
    for (int r = 0; r < 16; ++r) {
        const int q = (r & 3) + 8 * (r >> 2) + 4 * g;
        Os[wave][q][l] = O[r];
    }
    __syncthreads();

    // ---- pass A: cross-split reduce, pr = O*inv + wgt (in-place in Os[0]) ----
    const int qq = threadIdx.x >> 3;      // 0..31
    const int cg = threadIdx.x & 7;       // 0..7 -> cols cg*4..cg*4+3
    const float lsumT = Ls[0][qq] + Ls[1][qq] + Ls[2][qq] + Ls[3][qq];
    const int rid = b * NN + qt * 32 + qq;
    const float wgt = Wbuf[rid] * 0.1f;
    const float inv = 1.f / lsumT;
    {
        const float4 p0 = *(const float4*)&Os[0][qq][cg*4];
        const float4 p1 = *(const float4*)&Os[1][qq][cg*4];
        const float4 p2 = *(const float4*)&Os[2][qq][cg*4];
        const float4 p3 = *(const float4*)&Os[3][qq][cg*4];
        float4 pr;
        pr.x = fmaf(p0.x + p1.x + p2.x + p3.x, inv, wgt);
        pr.y = fmaf(p0.y + p1.y + p2.y + p3.y, inv, wgt);
        pr.z = fmaf(p0.z + p1.z + p2.z + p3.z, inv, wgt);
        pr.w = fmaf(p0.w + p1.w + p2.w + p3.w, inv, wgt);
        *(float4*)&Os[0][qq][cg*4] = pr;
    }
    __syncthreads();

    // ---- pass B: Wo GEMM + LayerNorm (32 values across 8 threads) ----
    float acc[4];
    #pragma unroll
    for (int j = 0; j < 4; ++j) acc[j] = bo[cg*4 + j];
    #pragma unroll
    for (int c = 0; c < 8; ++c) {
        const float4 pr = *(const float4*)&Os[0][qq][c*4];
        const float prv[4] = {pr.x, pr.y, pr.z, pr.w};
        #pragma unroll
        for (int i = 0; i < 4; ++i) {
            #pragma unroll
            for (int j = 0; j < 4; ++j)
                acc[j] = fmaf(prv[i], sWo[(c*4 + i)*HH + cg*4 + j], acc[j]);
        }
    }
    float ss = acc[0] + acc[1] + acc[2] + acc[3];
    float sq = acc[0]*acc[0] + acc[1]*acc[1] + acc[2]*acc[2] + acc[3]*acc[3];
    ss += __shfl_xor(ss, 1, 64); ss += __shfl_xor(ss, 2, 64); ss += __shfl_xor(ss, 4, 64);
    sq += __shfl_xor(sq, 1, 64); sq += __shfl_xor(sq, 2, 64); sq += __shfl_xor(sq, 4, 64);
    const float mean = ss * (1.f / HH);
    const float var  = sq * (1.f / HH) - mean * mean;
    const float rstd = rsqrtf(var + 1e-5f);

    float res[4];
    #pragma unroll
    for (int j = 0; j < 4; ++j)
        res[j] = (acc[j] - mean) * rstd * lng[cg*4 + j] + lnb[cg*4 + j];
    *(float4*)(out + (size_t)rid * HH + cg*4) =
        make_float4(res[0], res[1], res[2], res[3]);
}

// ---------------------------------------------------------------------------
extern "C" void kernel_launch(void* const* d_in, const int* in_sizes, int n_in,
                              void* d_out, int out_size, void* d_ws, size_t ws_size,
                              hipStream_t stream)
{
    const float* x    = (const float*)d_in[0];
    const float* feat = (const float*)d_in[1];
    const float* adj  = (const float*)d_in[2];
    const float* dlw  = (const float*)d_in[3];
    const float* aw   = (const float*)d_in[4];
    const float* Wk   = (const float*)d_in[5];
    const float* bk   = (const float*)d_in[6];
    const float* Wq   = (const float*)d_in[7];
    const float* bq   = (const float*)d_in[8];
    const float* Wv   = (const float*)d_in[9];
    const float* bv   = (const float*)d_in[10];
    const float* Wo   = (const float*)d_in[11];
    const float* bo   = (const float*)d_in[12];
    const float* lng  = (const float*)d_in[13];
    const float* lnb  = (const float*)d_in[14];

    h16* Qh   = (h16*)d_ws;                     // 524288 h16 (1 MB)
    h16* Kh   = Qh + 524288;                    // 1 MB
    h16* VTh  = Kh + 524288;                    // 1048576 h16 (2 MB)
    float* Wb = (float*)(VTh + 1048576);        // 32768 f32 (128 KB)
    h16* adjP = (h16*)(Wb + 32768);             // NN*NN h16 (8 MB), packed
    float* out = (float*)d_out;

    prep_kernel<<<1536, 256, 0, stream>>>(x, feat, dlw, aw, Wk, bk, Wq, bq,
                                          Wv, bv, adj, Qh, Kh, VTh, adjP, Wb);
    attn_kernel<<<64*16, 256, 0, stream>>>(Qh, Kh, VTh, adjP, Wb,
                                           Wo, bo, lng, lnb, out);
}